// Round 7
// baseline (3393.851 us; speedup 1.0000x reference)
//
#include <hip/hip_runtime.h>
#include <math.h>

// GRU: T=512, B=64, H=512, L=2. Single persistent fused kernel:
// 128 blocks = 64 layer-0 + 64 layer-1 (wavefront pipeline). Each block owns
// 8 hidden cols; 32 gate-rows = 8 cols x {r, z, n_x, n_h}. X-projection and
// H-dot are both MFMA (bf16), split X/H accumulators summed in the epilogue.
// Layer-0 X input = pre-transposed bf16 x (cached loads); layer-1 X input =
// layer-0's published bf16 h (sc1 loads). h exchanged via relaxed agent-scope
// (sc1) 8B atomics in MFMA B-fragment order. Compute core identical to the
// proven 2494us kernel (rounds 0/3).
//
// Round-7 change: DECOUPLED per-layer barriers + slack coupling.
//  - Each layer runs its own 64-block monotone atomic tree (8 leaves x 8 +
//    root 8 + gen word, s_sleep poll) at its own pace. gen = s+1 after
//    completing step s.
//  - Cross-layer coupling via the gen words only, with ring slack:
//      L1 step s: needs gen0 >= s      (h0^s available)        [tid0 poll]
//      L0 step s: needs gen1 >= s-2    (h0 4-ring overwrite ok) [pre-publish]
//    h0 ring 4-deep (slots s&3; semantics validated in rounds 1/5, both
//    PASSED), h1 ring 2-deep (internal to L1's lockstep).
//    Steady state (L1 lags 1-3): both checks already satisfied -> no spin.
//  - L1's Yout stores deferred to the START of the next step (value is hp,
//    already in-register), so the HBM write ack has a full step in flight
//    before the next barrier's vmcnt(0) drain instead of ~1k cycles.
//  Rationale: shared 128-wide barrier makes each step cost max(L0_i, L1_i)
//  (jitter adds over 513 steps); decoupling makes total ~ max(sum L0, sum L1).
//  No dispatch/placement/XCD assumptions anywhere (Guideline 16).

typedef short bf16x8 __attribute__((ext_vector_type(8)));
typedef float f32x4 __attribute__((ext_vector_type(4)));

__device__ __forceinline__ unsigned short f2bf(float f) {
  unsigned u = __builtin_bit_cast(unsigned, f);
  return (unsigned short)((u + 0x7fff + ((u >> 16) & 1)) >> 16);
}
__device__ __forceinline__ unsigned long long ldq(const unsigned long long* p) {
  return __hip_atomic_load(p, __ATOMIC_RELAXED, __HIP_MEMORY_SCOPE_AGENT);
}
__device__ __forceinline__ void stq(unsigned long long* p,
                                    unsigned long long v) {
  __hip_atomic_store(p, v, __ATOMIC_RELAXED, __HIP_MEMORY_SCOPE_AGENT);
}
__device__ __forceinline__ unsigned ldw(const unsigned* p) {
  return __hip_atomic_load(p, __ATOMIC_RELAXED, __HIP_MEMORY_SCOPE_AGENT);
}

// fragment-order: element (k,b) -> chunk*8 + (k&7)
__device__ __forceinline__ int hchunk(int k, int b) {
  return ((b >> 4) * 16 + (k >> 5)) * 64 + ((k >> 3) & 3) * 16 + (b & 15);
}

// Per-layer region (unsigned words, all lines 64B apart, monotone, zeroed by
// prep): rb + (blk&7)*16 leaves (8x8), rb+128 root, rb+144 gen.
__device__ __forceinline__ void layer_barrier(unsigned* rb, int blk,
                                              unsigned target) {
  __syncthreads();  // drains each wave's vmcnt: publishes globally visible
  if (threadIdx.x == 0) {
    unsigned prev = __hip_atomic_fetch_add(rb + (blk & 7) * 16, 1u,
                                           __ATOMIC_RELAXED,
                                           __HIP_MEMORY_SCOPE_AGENT);
    bool done = false;
    if ((prev & 7u) == 7u) {  // 8 blocks per leaf
      unsigned p2 = __hip_atomic_fetch_add(rb + 128, 1u, __ATOMIC_RELAXED,
                                           __HIP_MEMORY_SCOPE_AGENT);
      if ((p2 & 7u) == 7u) {  // 8 leaves
        __hip_atomic_store(rb + 144, target, __ATOMIC_RELAXED,
                           __HIP_MEMORY_SCOPE_AGENT);
        done = true;
      }
    }
    if (!done) {
      while (ldw(rb + 144) < target) __builtin_amdgcn_s_sleep(1);
    }
  }
  __syncthreads();
}

// ---------------------------------------------------------------- prep
// h0buf slot0 / h1buf slot0 <- bf16(init) fragment order; zero bar[0..511].
// grid 128x512.
__global__ void gru_prep_h(const float* __restrict__ init,
                           unsigned short* __restrict__ h0buf,
                           unsigned short* __restrict__ h1buf,
                           unsigned* __restrict__ bar) {
  int l = blockIdx.x >> 6;
  int idx = (blockIdx.x & 63) * 512 + threadIdx.x;  // 0..32767
  int k = idx >> 6, b = idx & 63;
  unsigned short v = f2bf(init[(size_t)l * 32768 + b * 512 + k]);
  unsigned short* dst = (l == 0) ? h0buf : h1buf;
  dst[hchunk(k, b) * 8 + (k & 7)] = v;
  if (blockIdx.x == 0 && threadIdx.x < 512) bar[threadIdx.x] = 0u;
}

// ---------------------------------------------------------------- x transpose
// xbf[t][ck*8+e] = bf16(x[t][b][k]) in fragment order. grid 512(t) x 512.
__global__ void gru_xprep(const float* __restrict__ x,
                          unsigned short* __restrict__ xbf) {
  int t = blockIdx.x;
#pragma unroll
  for (int it = 0; it < 8; ++it) {
    int ck = it * 512 + threadIdx.x;  // 0..4095
    int b = (ck >> 10) * 16 + (ck & 15);
    int k0 = ((ck >> 6) & 15) * 32 + ((ck >> 4) & 3) * 8;
    const float* src = x + ((size_t)t * 64 + b) * 512 + k0;
    float4 v0 = *(const float4*)(src);
    float4 v1 = *(const float4*)(src + 4);
    unsigned short o[8] = {f2bf(v0.x), f2bf(v0.y), f2bf(v0.z), f2bf(v0.w),
                           f2bf(v1.x), f2bf(v1.y), f2bf(v1.z), f2bf(v1.w)};
    *(uint4*)(xbf + (size_t)t * 32768 + ck * 8) = *(const uint4*)o;
  }
}

// ---------------------------------------------------------------- weight images
// wX/wH[l][blk][row][k] bf16, row = c*4+q, col = blk*8+c.
// wX rows: q={Wir,Wiz,Win,0}; wH rows: q={Whr,Whz,0,Whn}. grid 128 x 256.
__global__ void gru_wimg(const float* __restrict__ Wir,
                         const float* __restrict__ Wiz,
                         const float* __restrict__ Win,
                         const float* __restrict__ Whr,
                         const float* __restrict__ Whz,
                         const float* __restrict__ Whn,
                         unsigned short* __restrict__ wX,
                         unsigned short* __restrict__ wH) {
  int l = blockIdx.x >> 6, blk = blockIdx.x & 63;
  size_t base = ((size_t)l * 64 + blk) * 32 * 512;
  size_t wbase = (size_t)l * 512 * 512;
  for (int idx = threadIdx.x; idx < 16384; idx += 256) {
    int c = idx & 7, k = (idx >> 3) & 511, q = idx >> 12;
    int col = blk * 8 + c;
    int row = c * 4 + q;
    size_t we = wbase + (size_t)k * 512 + col;
    float vx = 0.f, vh = 0.f;
    if (q == 0) { vx = Wir[we]; vh = Whr[we]; }
    else if (q == 1) { vx = Wiz[we]; vh = Whz[we]; }
    else if (q == 2) { vx = Win[we]; }
    else { vh = Whn[we]; }
    wX[base + (size_t)row * 512 + k] = f2bf(vx);
    wH[base + (size_t)row * 512 + k] = f2bf(vh);
  }
}

// ---------------------------------------------------------------- fused recurrence
// 128 blocks x 512 threads. role = blk>>6 (0: layer0, 1: layer1).
// Wave wv: Nt = wv&3 (16-batch tile), Kh = wv>>2 (K half). A-frags in VGPRs.
__global__ __launch_bounds__(512, 1) void gru_recur_fused(
    const unsigned short* __restrict__ xbf,  // [512][32768]
    const unsigned short* __restrict__ wX,   // [2][64][32][512]
    const unsigned short* __restrict__ wH,
    const float* __restrict__ bir, const float* __restrict__ bhr,
    const float* __restrict__ biz, const float* __restrict__ bhz,
    const float* __restrict__ bin_, const float* __restrict__ bhn,
    const float* __restrict__ init,  // [2][64][512]
    unsigned short* h0buf,  // ring of 4 x 32768
    unsigned short* h1buf,  // ring of 2 x 32768
    float* __restrict__ Yout, float* __restrict__ finals, unsigned* bar) {
  __shared__ float ghp[2][32][66];          // [Kh][row][b]
  __shared__ unsigned short hpack[64 * 8];  // [b][c]
  const int tid = threadIdx.x;
  const int lane = tid & 63;
  const int wv = tid >> 6;  // 0..7
  const int Nt = wv & 3, Kh = wv >> 2;
  const int quad = lane >> 4, mm = lane & 15;
  const int role = blockIdx.x >> 6;  // block-uniform
  const int blk = blockIdx.x & 63;
  const int cg0 = blk * 8;
  const int c = wv, bb = lane;
  const int cg = cg0 + c;
  const float bR = bir[role * 512 + cg] + bhr[role * 512 + cg];
  const float bZ = biz[role * 512 + cg] + bhz[role * 512 + cg];
  const float bNX = bin_[role * 512 + cg];
  const float bNH = bhn[role * 512 + cg];
  unsigned* rb = bar + role * 256;        // own layer's barrier region
  const unsigned* gen0 = bar + 144;       // layer-0 progress word
  const unsigned* gen1 = bar + 256 + 144; // layer-1 progress word

  // ---- A-fragments: X-image and H-image, 2 Mtiles x 8 Ksteps each
  bf16x8 aX0[8], aX1[8], aH0[8], aH1[8];
  {
    const unsigned short* wXb = wX + ((size_t)role * 64 + blk) * 32 * 512;
    const unsigned short* wHb = wH + ((size_t)role * 64 + blk) * 32 * 512;
#pragma unroll
    for (int j = 0; j < 8; ++j) {
      int ko = (Kh * 8 + j) * 32 + quad * 8;
      aX0[j] = *(const bf16x8*)(wXb + (size_t)mm * 512 + ko);
      aX1[j] = *(const bf16x8*)(wXb + (size_t)(16 + mm) * 512 + ko);
      aH0[j] = *(const bf16x8*)(wHb + (size_t)mm * 512 + ko);
      aH1[j] = *(const bf16x8*)(wHb + (size_t)(16 + mm) * 512 + ko);
    }
  }
  float hp = init[(size_t)role * 32768 + bb * 512 + cg];

  const int sBeg = (role == 0) ? 0 : 1;
  const int sEnd = (role == 0) ? 511 : 512;
  for (int s = sBeg; s <= sEnd; ++s) {
    const int t = (role == 0) ? s : s - 1;
    if (role == 1) {
      // ---- deferred Yout for t = s-2 (value is hp from last step): gets a
      // full step in flight before the next barrier's vmcnt drain.
      if (s >= 2) Yout[((size_t)(s - 2) * 64 + bb) * 512 + cg] = hp;
      // ---- cross-layer wait: h0^s must be published (gen0 >= s).
      // Steady state (L0 ahead): satisfied on first load.
      if (tid == 0) {
        while (ldw(gen0) < (unsigned)s) __builtin_amdgcn_s_sleep(1);
      }
      __syncthreads();
    }
    const unsigned long long* Xq =
        (const unsigned long long*)((role == 0)
                                        ? (xbf + (size_t)t * 32768)
                                        : (h0buf + (size_t)(s & 3) * 32768));
    const unsigned long long* Hq =
        (const unsigned long long*)((role == 0)
                                        ? (h0buf + (size_t)(s & 3) * 32768)
                                        : (h1buf + (size_t)(t & 1) * 32768));
    unsigned short* Hdst = (role == 0)
                               ? (h0buf + (size_t)((s + 1) & 3) * 32768)
                               : (h1buf + (size_t)((t + 1) & 1) * 32768);
    // ---- B-fragment loads (all independent, in flight together)
    unsigned long long xq[16], hq[16];
#pragma unroll
    for (int j = 0; j < 8; ++j) {
      int base = ((Nt * 16 + Kh * 8 + j) * 64 + lane) << 1;
      if (role == 0) {  // cached loads (static xbf)
        xq[2 * j] = Xq[base];
        xq[2 * j + 1] = Xq[base + 1];
      } else {  // sc1 (published h0)
        xq[2 * j] = ldq(Xq + base);
        xq[2 * j + 1] = ldq(Xq + base + 1);
      }
      hq[2 * j] = ldq(Hq + base);
      hq[2 * j + 1] = ldq(Hq + base + 1);
    }
    // ---- MFMA: split X/H accumulators (halves dependent-chain depth)
    f32x4 a0x = {0.f, 0.f, 0.f, 0.f}, a0h = {0.f, 0.f, 0.f, 0.f};
    f32x4 a1x = {0.f, 0.f, 0.f, 0.f}, a1h = {0.f, 0.f, 0.f, 0.f};
#pragma unroll
    for (int j = 0; j < 8; ++j) {
      union { unsigned long long q[2]; bf16x8 v; } ux, uh;
      ux.q[0] = xq[2 * j]; ux.q[1] = xq[2 * j + 1];
      uh.q[0] = hq[2 * j]; uh.q[1] = hq[2 * j + 1];
      a0x = __builtin_amdgcn_mfma_f32_16x16x32_bf16(aX0[j], ux.v, a0x, 0, 0, 0);
      a1x = __builtin_amdgcn_mfma_f32_16x16x32_bf16(aX1[j], ux.v, a1x, 0, 0, 0);
      a0h = __builtin_amdgcn_mfma_f32_16x16x32_bf16(aH0[j], uh.v, a0h, 0, 0, 0);
      a1h = __builtin_amdgcn_mfma_f32_16x16x32_bf16(aH1[j], uh.v, a1h, 0, 0, 0);
    }
    f32x4 acc0 = a0x + a0h, acc1 = a1x + a1h;
    // ---- D -> LDS (C/D: col=lane&15, row=quad*4+reg)
    {
      float* g = &ghp[Kh][0][0];
      int ncol = Nt * 16 + mm;
#pragma unroll
      for (int r = 0; r < 4; ++r) g[(quad * 4 + r) * 66 + ncol] = acc0[r];
#pragma unroll
      for (int r = 0; r < 4; ++r)
        g[(16 + quad * 4 + r) * 66 + ncol] = acc1[r];
    }
    __syncthreads();
    // ---- epilogue: thread owns (col c, batch bb)
    {
      float gr = ghp[0][c * 4 + 0][bb] + ghp[1][c * 4 + 0][bb];
      float gz = ghp[0][c * 4 + 1][bb] + ghp[1][c * 4 + 1][bb];
      float gnx = ghp[0][c * 4 + 2][bb] + ghp[1][c * 4 + 2][bb];
      float gnh = ghp[0][c * 4 + 3][bb] + ghp[1][c * 4 + 3][bb];
      float r = 1.0f / (1.0f + expf(-(gr + bR)));
      float z = 1.0f / (1.0f + expf(-(gz + bZ)));
      float n = tanhf(gnx + bNX + r * (gnh + bNH));
      float hnew = (1.0f - z) * n + z * hp;
      hp = hnew;
      hpack[bb * 8 + c] = f2bf(hnew);
      if (role == 0 && t == 511) finals[bb * 512 + cg] = hnew;
      // role-1 Yout/finals are deferred (top of next step / post-loop)
    }
    __syncthreads();
    // ---- publish new h (bf16 fragment order), wave 0. Layer-0 first
    // checks ring safety: overwriting h0 slot (s+1)&3 (= h0^{s-3}) needs
    // layer-1 done with step s-3, i.e. gen1 >= s-2. Steady state: satisfied.
    if (tid < 64) {
      if (role == 0 && s >= 3) {
        while (ldw(gen1) < (unsigned)(s - 2)) __builtin_amdgcn_s_sleep(1);
      }
      int ck = ((tid >> 4) * 16 + (cg0 >> 5)) * 64 + ((cg0 >> 3) & 3) * 16 +
               (tid & 15);
      const unsigned long long* src =
          (const unsigned long long*)(hpack + tid * 8);
      unsigned long long* dst = (unsigned long long*)(Hdst + (size_t)ck * 8);
      stq(dst, src[0]);
      stq(dst + 1, src[1]);
    }
    // ---- own-layer barrier (64-wide tree); publishes drained by its
    // first __syncthreads, then gen = s+1.
    layer_barrier(rb, blk, (unsigned)(s + 1));
  }
  // ---- role-1 tail: last Yout column (t=511) + finals
  if (role == 1) {
    Yout[((size_t)511 * 64 + bb) * 512 + cg] = hp;
    finals[32768 + bb * 512 + cg] = hp;
  }
}

// ---------------------------------------------------------------- launch
extern "C" void kernel_launch(void* const* d_in, const int* in_sizes, int n_in,
                              void* d_out, int out_size, void* d_ws,
                              size_t ws_size, hipStream_t stream) {
  const float* x = (const float*)d_in[0];
  const float* init = (const float*)d_in[1];
  const float* w_ir = (const float*)d_in[2];
  const float* w_hr = (const float*)d_in[3];
  const float* w_iz = (const float*)d_in[4];
  const float* w_hz = (const float*)d_in[5];
  const float* w_in_ = (const float*)d_in[6];
  const float* w_hn = (const float*)d_in[7];
  const float* b_ir = (const float*)d_in[8];
  const float* b_hr = (const float*)d_in[9];
  const float* b_iz = (const float*)d_in[10];
  const float* b_hz = (const float*)d_in[11];
  const float* b_in_ = (const float*)d_in[12];
  const float* b_hn = (const float*)d_in[13];
  float* out = (float*)d_out;
  float* Y = out;                                // [T,B,H] = layer-1 outputs
  float* finals = out + (size_t)512 * 64 * 512;  // [L,B,H]

  // workspace layout (ushorts unless noted)
  unsigned short* xbf = (unsigned short*)d_ws;            // 512*32768
  unsigned short* wX = xbf + (size_t)512 * 32768;         // 2*64*32*512
  unsigned short* wH = wX + (size_t)2 * 64 * 32 * 512;
  unsigned short* h0buf = wH + (size_t)2 * 64 * 32 * 512; // 4*32768 (ring)
  unsigned short* h1buf = h0buf + (size_t)4 * 32768;      // 2*32768
  unsigned* bar = (unsigned*)(h1buf + 2 * 32768);         // 512 words

  gru_prep_h<<<128, 512, 0, stream>>>(init, h0buf, h1buf, bar);
  gru_xprep<<<512, 512, 0, stream>>>(x, xbf);
  gru_wimg<<<128, 256, 0, stream>>>(w_ir, w_iz, w_in_, w_hr, w_hz, w_hn, wX,
                                    wH);
  gru_recur_fused<<<128, 512, 0, stream>>>(
      xbf, wX, wH, b_ir, b_hr, b_iz, b_hz, b_in_, b_hn, init, h0buf, h1buf, Y,
      finals, bar);
}